// Round 3
// baseline (305.559 us; speedup 1.0000x reference)
//
#include <hip/hip_runtime.h>
#include <math.h>

namespace {

constexpr int NATOM = 512;
constexpr float STEP = 10.0f / 63.0f;

typedef float f32x4 __attribute__((ext_vector_type(4)));
typedef short s16x8 __attribute__((ext_vector_type(8)));

struct Ptrs { const float* p[19]; };

// input index map:
// 0 geometry [512,3]; 1 x0 [512,32,1]; 2 x1 [512,32,3]
// then per net q in {f0,fa,fb,fc}: 3+4q w1[64,64]; 4+4q b1[64]; 5+4q w2[32,64]; 6+4q b2[32]

__device__ __forceinline__ unsigned f2bf(float f) {
  union { float f; unsigned u; } v; v.f = f;
  return (v.u + 0x7fffu + ((v.u >> 16) & 1u)) >> 16;  // RNE
}

__global__ __launch_bounds__(512, 4)
void tfn_fused(Ptrs A, float* __restrict__ out) {
  const int a    = blockIdx.x;
  const int tid  = threadIdx.x;
  const int wv   = tid >> 6;
  const int w    = wv & 3;        // net: 0=f0 1=fa 2=fb 3=fc
  const int mh   = wv >> 2;       // b-half of the 32-neighbor tile
  const int lane = tid & 63;
  const int ln   = lane & 15;
  const int hi   = lane >> 4;     // 0..3

  // ---------------- LDS (~29.4 KB; 2 blocks/CU trivially fit) ----------------
  __shared__ __align__(16) short rbf_frag[2][2][2][64][8]; // [dbuf][kt][mt][lane][8] bf16, frag-order (lane-linear)
  __shared__ __align__(16) float u_lds[2][32][4];          // [dbuf][b][xyz-]
  __shared__ __align__(16) short h_s[4 * 32 * 72];         // per-net h, XOR-swizzled chunks, row=144B
  __shared__ __align__(16) float scr[4][16][8];            // mh-pair combine

  const float* __restrict__ geom = A.p[0];
  const float* __restrict__ x0g  = A.p[1];
  const float* __restrict__ x1g  = A.p[2];

  // ---------------- persistent register B-fragments (weights, bf16) ----------------
  // H[b][j] = sum_k RBF[b][k] * W1[j][k]  -> B-frag[k][n=j]: lane holds col j=nt*16+ln, k=kt*32+hi*8..
  s16x8 w1f[4][2];
  {
    const float* w1p = A.p[3 + 4 * w];
    #pragma unroll
    for (int nt = 0; nt < 4; ++nt)
      #pragma unroll
      for (int kt = 0; kt < 2; ++kt) {
        const float* src = w1p + (nt * 16 + ln) * 64 + kt * 32 + hi * 8;
        s16x8 f;
        #pragma unroll
        for (int i = 0; i < 8; ++i) f[i] = (short)f2bf(src[i]);
        w1f[nt][kt] = f;
      }
  }
  float b1v[4];
  {
    const float* b1p = A.p[4 + 4 * w];
    #pragma unroll
    for (int nt = 0; nt < 4; ++nt) b1v[nt] = b1p[nt * 16 + ln];
  }
  // RAD[b][c] = sum_j H[b][j] * W2[c][j] -> B-frag lane holds col c=nt*16+ln
  s16x8 w2f[2][2];
  {
    const float* w2p = A.p[5 + 4 * w];
    #pragma unroll
    for (int nt = 0; nt < 2; ++nt)
      #pragma unroll
      for (int kt = 0; kt < 2; ++kt) {
        const float* src = w2p + (nt * 16 + ln) * 64 + kt * 32 + hi * 8;
        s16x8 f;
        #pragma unroll
        for (int i = 0; i < 8; ++i) f[i] = (short)f2bf(src[i]);
        w2f[nt][kt] = f;
      }
  }
  float b2v[2];
  {
    const float* b2p = A.p[6 + 4 * w];
    b2v[0] = b2p[ln]; b2v[1] = b2p[16 + ln];
  }

  const float gax = geom[3*a+0], gay = geom[3*a+1], gaz = geom[3*a+2];

  float av[8] = {0.f,0.f,0.f,0.f,0.f,0.f,0.f,0.f};

  for (int t = 0; t < 16; ++t) {
    const int b0  = t * 32;
    const int buf = t & 1;
    const int bb4 = b0 + mh * 16 + hi * 4;   // stage-3 b-base for this lane

    // ---- stage-3 x prefetch for c = ln (issued early; consumed after MFMA) ----
    float x0r0[4], x1r0[4][3];
    if (w <= 1) {                       // roles needing x0 (f0, fa)
      const float* p = x0g + bb4 * 32 + ln;
      #pragma unroll
      for (int e = 0; e < 4; ++e) x0r0[e] = p[e * 32];
    }
    if (w != 1) {                       // roles needing x1 (f0, fb, fc)
      const float* p = x1g + bb4 * 96 + ln * 3;
      #pragma unroll
      for (int e = 0; e < 4; ++e) {
        x1r0[e][0] = p[e*96+0]; x1r0[e][1] = p[e*96+1]; x1r0[e][2] = p[e*96+2];
      }
    }

    // ---------------- Phase A: rbf (frag-order bf16) + unit vectors ----------------
    {
      const int bb = tid & 31;          // neighbor in tile
      const int kq = tid >> 5;          // rbf quad 0..15 (4 centers each)
      const int bg = b0 + bb;
      const float dx = gax - geom[3*bg+0];
      const float dy = gay - geom[3*bg+1];
      const float dz = gaz - geom[3*bg+2];
      const float r2 = dx*dx + dy*dy + dz*dz;
      const float dij = sqrtf(fmaxf(r2, 1e-8f));
      const float d0 = dij - STEP * (float)(4 * kq);
      const float d1 = d0 - STEP, d2 = d0 - 2.f*STEP, d3 = d0 - 3.f*STEP;
      const unsigned lo = f2bf(__expf(-10.f*d0*d0)) | (f2bf(__expf(-10.f*d1*d1)) << 16);
      const unsigned hi2 = f2bf(__expf(-10.f*d2*d2)) | (f2bf(__expf(-10.f*d3*d3)) << 16);
      uint2 pk; pk.x = lo; pk.y = hi2;
      // frag address: kt=kq>>3, mt=bb>>4, fraglane=((kq>>1)&3)*16+(bb&15), half=kq&1
      *(uint2*)&rbf_frag[buf][kq >> 3][bb >> 4][((kq >> 1) & 3) * 16 + (bb & 15)][(kq & 1) * 4] = pk;
      if (kq == 0) {
        const float inv = 1.0f / sqrtf(r2 + 1e-8f);   // exactly 0*inv=0 on diagonal -> self-mask free
        f32x4 uv; uv[0] = dx*inv; uv[1] = dy*inv; uv[2] = dz*inv; uv[3] = 0.f;
        *(f32x4*)&u_lds[buf][bb][0] = uv;
      }
    }
    __syncthreads();   // the only barrier per tile

    // ---------------- Stage 1: H = relu(RBF . W1^T + b1) ----------------
    const s16x8 af0 = *(const s16x8*)&rbf_frag[buf][0][mh][lane][0];  // lane-linear, conflict-free
    const s16x8 af1 = *(const s16x8*)&rbf_frag[buf][1][mh][lane][0];
    f32x4 acc1[4] = {};
    #pragma unroll
    for (int nt = 0; nt < 4; ++nt)
      acc1[nt] = __builtin_amdgcn_mfma_f32_16x16x32_bf16(af0, w1f[nt][0], acc1[nt], 0, 0, 0);
    #pragma unroll
    for (int nt = 0; nt < 4; ++nt)
      acc1[nt] = __builtin_amdgcn_mfma_f32_16x16x32_bf16(af1, w1f[nt][1], acc1[nt], 0, 0, 0);
    // epilogue: bias+relu+cvt, XOR-swizzled scatter (own-wave rows only -> no barrier)
    #pragma unroll
    for (int nt = 0; nt < 4; ++nt) {
      const int j = nt * 16 + ln;
      #pragma unroll
      for (int r = 0; r < 4; ++r) {
        const int bl = mh * 16 + hi * 4 + r;
        h_s[(w * 32 + bl) * 72 + (((j >> 3) ^ (bl & 7)) << 3) + (j & 7)] =
            (short)f2bf(fmaxf(acc1[nt][r] + b1v[nt], 0.0f));
      }
    }

    // ---------------- Stage 2: RAD = H . W2^T + b2 (rad stays in registers) ----------------
    const int hbase = (w * 32 + mh * 16 + ln) * 72;
    const s16x8 a20 = *(const s16x8*)&h_s[hbase + (((0 + hi) ^ (ln & 7)) << 3)];
    const s16x8 a21 = *(const s16x8*)&h_s[hbase + (((4 + hi) ^ (ln & 7)) << 3)];
    f32x4 acc2[2] = {};
    acc2[0] = __builtin_amdgcn_mfma_f32_16x16x32_bf16(a20, w2f[0][0], acc2[0], 0, 0, 0);
    acc2[1] = __builtin_amdgcn_mfma_f32_16x16x32_bf16(a20, w2f[1][0], acc2[1], 0, 0, 0);
    acc2[0] = __builtin_amdgcn_mfma_f32_16x16x32_bf16(a21, w2f[0][1], acc2[0], 0, 0, 0);
    acc2[1] = __builtin_amdgcn_mfma_f32_16x16x32_bf16(a21, w2f[1][1], acc2[1], 0, 0, 0);
    float rad0[4], rad1[4];
    #pragma unroll
    for (int e = 0; e < 4; ++e) { rad0[e] = acc2[0][e] + b2v[0]; rad1[e] = acc2[1][e] + b2v[1]; }
    // lane (ln,hi) now holds rad[c=ln | 16+ln][b = bb4..bb4+3] -- exactly stage-3 ownership.

    // ---- u + second-channel x loads ----
    float uu[4][3];
    if (w != 0) {
      #pragma unroll
      for (int e = 0; e < 4; ++e) {
        const f32x4 uv = *(const f32x4*)&u_lds[buf][mh * 16 + hi * 4 + e][0];  // 4-addr broadcast
        uu[e][0] = uv[0]; uu[e][1] = uv[1]; uu[e][2] = uv[2];
      }
    }
    float x0r1[4], x1r1[4][3];
    if (w <= 1) {
      const float* p = x0g + bb4 * 32 + 16 + ln;
      #pragma unroll
      for (int e = 0; e < 4; ++e) x0r1[e] = p[e * 32];
    }
    if (w != 1) {
      const float* p = x1g + bb4 * 96 + (16 + ln) * 3;
      #pragma unroll
      for (int e = 0; e < 4; ++e) {
        x1r1[e][0] = p[e*96+0]; x1r1[e][1] = p[e*96+1]; x1r1[e][2] = p[e*96+2];
      }
    }

    // ---------------- Stage 3: per-wave equivariant accumulation (pure registers) ----------------
    if (w == 0) {            // r0: out0_a += r0*x0 ; out1_b += r0*x1
      #pragma unroll
      for (int e = 0; e < 4; ++e) {
        const float r = rad0[e];
        av[0] = fmaf(r, x0r0[e],    av[0]);
        av[1] = fmaf(r, x1r0[e][0], av[1]);
        av[2] = fmaf(r, x1r0[e][1], av[2]);
        av[3] = fmaf(r, x1r0[e][2], av[3]);
        const float s = rad1[e];
        av[4] = fmaf(s, x0r1[e],    av[4]);
        av[5] = fmaf(s, x1r1[e][0], av[5]);
        av[6] = fmaf(s, x1r1[e][1], av[6]);
        av[7] = fmaf(s, x1r1[e][2], av[7]);
      }
    } else if (w == 1) {     // ra: out1_a += ra*x0*u
      #pragma unroll
      for (int e = 0; e < 4; ++e) {
        const float rx0 = rad0[e] * x0r0[e];
        av[0] = fmaf(rx0, uu[e][0], av[0]);
        av[1] = fmaf(rx0, uu[e][1], av[1]);
        av[2] = fmaf(rx0, uu[e][2], av[2]);
        const float rx1 = rad1[e] * x0r1[e];
        av[3] = fmaf(rx1, uu[e][0], av[3]);
        av[4] = fmaf(rx1, uu[e][1], av[4]);
        av[5] = fmaf(rx1, uu[e][2], av[5]);
      }
    } else if (w == 2) {     // rb: out0_b += rb*(u . x1)
      #pragma unroll
      for (int e = 0; e < 4; ++e) {
        const float dot0 = fmaf(uu[e][0], x1r0[e][0], fmaf(uu[e][1], x1r0[e][1], uu[e][2] * x1r0[e][2]));
        av[0] = fmaf(rad0[e], dot0, av[0]);
        const float dot1 = fmaf(uu[e][0], x1r1[e][0], fmaf(uu[e][1], x1r1[e][1], uu[e][2] * x1r1[e][2]));
        av[1] = fmaf(rad1[e], dot1, av[1]);
      }
    } else {                 // rc: out1_c += rc*(u x x1)
      #pragma unroll
      for (int e = 0; e < 4; ++e) {
        #pragma unroll
        for (int i = 0; i < 3; ++i) {
          const int j = (i + 1) % 3, k = (i + 2) % 3;
          const float cr0 = fmaf(uu[e][j], x1r0[e][k], -(uu[e][k] * x1r0[e][j]));
          av[i] = fmaf(rad0[e], cr0, av[i]);
          const float cr1 = fmaf(uu[e][j], x1r1[e][k], -(uu[e][k] * x1r1[e][j]));
          av[3 + i] = fmaf(rad1[e], cr1, av[3 + i]);
        }
      }
    }
  }

  // ---------------- reduce over hi (shfl) and mh (LDS), then store ----------------
  #pragma unroll
  for (int q = 0; q < 8; ++q) {
    av[q] += __shfl_xor(av[q], 16);
    av[q] += __shfl_xor(av[q], 32);
  }
  if (mh == 1 && hi == 0) {
    #pragma unroll
    for (int q = 0; q < 8; ++q) scr[w][ln][q] = av[q];
  }
  __syncthreads();
  if (mh == 0 && hi == 0) {
    #pragma unroll
    for (int q = 0; q < 8; ++q) av[q] += scr[w][ln][q];
    float* o1 = out + NATOM * 64 + a * 288;   // out1 [512][96][3]
    if (w == 0) {
      out[a * 64 + ln]      = av[0];
      o1[(32 + ln) * 3 + 0] = av[1]; o1[(32 + ln) * 3 + 1] = av[2]; o1[(32 + ln) * 3 + 2] = av[3];
      out[a * 64 + 16 + ln] = av[4];
      o1[(48 + ln) * 3 + 0] = av[5]; o1[(48 + ln) * 3 + 1] = av[6]; o1[(48 + ln) * 3 + 2] = av[7];
    } else if (w == 1) {
      o1[(     ln) * 3 + 0] = av[0]; o1[(     ln) * 3 + 1] = av[1]; o1[(     ln) * 3 + 2] = av[2];
      o1[(16 + ln) * 3 + 0] = av[3]; o1[(16 + ln) * 3 + 1] = av[4]; o1[(16 + ln) * 3 + 2] = av[5];
    } else if (w == 2) {
      out[a * 64 + 32 + ln] = av[0];
      out[a * 64 + 48 + ln] = av[1];
    } else {
      o1[(64 + ln) * 3 + 0] = av[0]; o1[(64 + ln) * 3 + 1] = av[1]; o1[(64 + ln) * 3 + 2] = av[2];
      o1[(80 + ln) * 3 + 0] = av[3]; o1[(80 + ln) * 3 + 1] = av[4]; o1[(80 + ln) * 3 + 2] = av[5];
    }
  }
}

} // namespace

extern "C" void kernel_launch(void* const* d_in, const int* in_sizes, int n_in,
                              void* d_out, int out_size, void* d_ws, size_t ws_size,
                              hipStream_t stream) {
  (void)in_sizes; (void)n_in; (void)d_ws; (void)ws_size; (void)out_size;
  Ptrs A;
  for (int i = 0; i < 19; ++i) A.p[i] = (const float*)d_in[i];
  tfn_fused<<<dim3(NATOM), dim3(512), 0, stream>>>(A, (float*)d_out);
}

// Round 5
// 302.710 us; speedup vs baseline: 1.0094x; 1.0094x over previous
//
#include <hip/hip_runtime.h>
#include <math.h>

namespace {

constexpr int NATOM = 512;
constexpr float STEP = 10.0f / 63.0f;

typedef float f32x4 __attribute__((ext_vector_type(4)));
typedef short s16x8 __attribute__((ext_vector_type(8)));

struct Ptrs { const float* p[19]; };

// input index map:
// 0 geometry [512,3]; 1 x0 [512,32,1]; 2 x1 [512,32,3]
// then per net q in {f0,fa,fb,fc}: 3+4q w1[64,64]; 4+4q b1[64]; 5+4q w2[32,64]; 6+4q b2[32]

__device__ __forceinline__ unsigned f2bf(float f) {
  union { float f; unsigned u; } v; v.f = f;
  return (v.u + 0x7fffu + ((v.u >> 16) & 1u)) >> 16;  // RNE
}

__global__ __launch_bounds__(512, 4)
void tfn_fused(Ptrs A, float* __restrict__ out) {
  const int a    = blockIdx.x;
  const int tid  = threadIdx.x;
  const int wv   = tid >> 6;
  const int w    = wv & 3;        // net: 0=f0 1=fa 2=fb 3=fc
  const int mh   = wv >> 2;       // b-half of the 32-neighbor tile
  const int lane = tid & 63;
  const int ln   = lane & 15;
  const int hi   = lane >> 4;     // 0..3

  // ---------------- LDS (~63 KB; 2 blocks/CU) ----------------
  __shared__ __align__(16) short rbf_frag[2][2][2][64][8]; // [dbuf][kt][mt][lane][8] bf16 frag-order
  __shared__ __align__(16) float u_lds[2][32][4];          // [dbuf][b][xyz-]
  __shared__ __align__(16) short h_s[4 * 32 * 72];         // per-net h, XOR-swizzled chunks
  __shared__ __align__(16) float x0_s[2][32][36];          // [dbuf][b][c] pad->stride 36 (4 mod 32)
  __shared__ __align__(16) float x1_s[2][32][100];         // [dbuf][b][c*3+i] pad->stride 100 (4 mod 32)
  __shared__ __align__(16) float scr[4][16][8];            // mh-pair combine

  const float* __restrict__ geom = A.p[0];
  const float* __restrict__ x0g  = A.p[1];
  const float* __restrict__ x1g  = A.p[2];

  // ---------------- persistent register B-fragments (weights, bf16) ----------------
  s16x8 w1f[4][2];
  {
    const float* w1p = A.p[3 + 4 * w];
    #pragma unroll
    for (int nt = 0; nt < 4; ++nt)
      #pragma unroll
      for (int kt = 0; kt < 2; ++kt) {
        const float* src = w1p + (nt * 16 + ln) * 64 + kt * 32 + hi * 8;
        s16x8 f;
        #pragma unroll
        for (int i = 0; i < 8; ++i) f[i] = (short)f2bf(src[i]);
        w1f[nt][kt] = f;
      }
  }
  float b1v[4];
  {
    const float* b1p = A.p[4 + 4 * w];
    #pragma unroll
    for (int nt = 0; nt < 4; ++nt) b1v[nt] = b1p[nt * 16 + ln];
  }
  s16x8 w2f[2][2];
  {
    const float* w2p = A.p[5 + 4 * w];
    #pragma unroll
    for (int nt = 0; nt < 2; ++nt)
      #pragma unroll
      for (int kt = 0; kt < 2; ++kt) {
        const float* src = w2p + (nt * 16 + ln) * 64 + kt * 32 + hi * 8;
        s16x8 f;
        #pragma unroll
        for (int i = 0; i < 8; ++i) f[i] = (short)f2bf(src[i]);
        w2f[nt][kt] = f;
      }
  }
  float b2v[2];
  {
    const float* b2p = A.p[6 + 4 * w];
    b2v[0] = b2p[ln]; b2v[1] = b2p[16 + ln];
  }

  const float gax = geom[3*a+0], gay = geom[3*a+1], gaz = geom[3*a+2];

  const int sb = tid >> 4;        // staging row (neighbor in tile)
  const int sc = tid & 15;        // staging col group

  float av[8] = {0.f,0.f,0.f,0.f,0.f,0.f,0.f,0.f};

  for (int t = 0; t < 16; ++t) {
    const int b0  = t * 32;
    const int buf = t & 1;

    // ---------------- Phase A: staging (rbf frag-order, u, x0, x1) ----------------
    {
      // x0 tile [32][32] -> x0_s (coalesced 64B-segment reads, ~2-way LDS writes)
      #pragma unroll
      for (int s = 0; s < 2; ++s)
        x0_s[buf][sb][sc + 16 * s] = x0g[(b0 + sb) * 32 + sc + 16 * s];
      // x1 tile [32][96] -> x1_s
      #pragma unroll
      for (int s = 0; s < 6; ++s)
        x1_s[buf][sb][sc + 16 * s] = x1g[(b0 + sb) * 96 + sc + 16 * s];

      const int bb = tid & 31;          // neighbor in tile
      const int kq = tid >> 5;          // rbf quad 0..15 (4 centers each)
      const int bg = b0 + bb;
      const float dx = gax - geom[3*bg+0];
      const float dy = gay - geom[3*bg+1];
      const float dz = gaz - geom[3*bg+2];
      const float r2 = dx*dx + dy*dy + dz*dz;
      const float dij = sqrtf(fmaxf(r2, 1e-8f));
      const float d0 = dij - STEP * (float)(4 * kq);
      const float d1 = d0 - STEP, d2 = d0 - 2.f*STEP, d3 = d0 - 3.f*STEP;
      const unsigned lo  = f2bf(__expf(-10.f*d0*d0)) | (f2bf(__expf(-10.f*d1*d1)) << 16);
      const unsigned hi2 = f2bf(__expf(-10.f*d2*d2)) | (f2bf(__expf(-10.f*d3*d3)) << 16);
      uint2 pk; pk.x = lo; pk.y = hi2;
      // frag address: kt=kq>>3, mt=bb>>4, fraglane=((kq>>1)&3)*16+(bb&15), half=kq&1
      *(uint2*)&rbf_frag[buf][kq >> 3][bb >> 4][((kq >> 1) & 3) * 16 + (bb & 15)][(kq & 1) * 4] = pk;
      if (kq == 0) {
        const float inv = 1.0f / sqrtf(r2 + 1e-8f);   // 0*inv=0 on diagonal -> self-mask free
        f32x4 uv; uv[0] = dx*inv; uv[1] = dy*inv; uv[2] = dz*inv; uv[3] = 0.f;
        *(f32x4*)&u_lds[buf][bb][0] = uv;
      }
    }
    __syncthreads();   // the only barrier per tile (2-deep dbuf makes it race-free)

    // ---------------- Stage 1: H = relu(RBF . W1^T + b1) ----------------
    const s16x8 af0 = *(const s16x8*)&rbf_frag[buf][0][mh][lane][0];  // lane-linear, conflict-free
    const s16x8 af1 = *(const s16x8*)&rbf_frag[buf][1][mh][lane][0];
    f32x4 acc1[4] = {};
    #pragma unroll
    for (int nt = 0; nt < 4; ++nt)
      acc1[nt] = __builtin_amdgcn_mfma_f32_16x16x32_bf16(af0, w1f[nt][0], acc1[nt], 0, 0, 0);
    #pragma unroll
    for (int nt = 0; nt < 4; ++nt)
      acc1[nt] = __builtin_amdgcn_mfma_f32_16x16x32_bf16(af1, w1f[nt][1], acc1[nt], 0, 0, 0);
    // bias+relu+cvt, XOR-swizzled scatter (own-wave rows only -> no barrier)
    #pragma unroll
    for (int nt = 0; nt < 4; ++nt) {
      const int j = nt * 16 + ln;
      #pragma unroll
      for (int r = 0; r < 4; ++r) {
        const int bl = mh * 16 + hi * 4 + r;
        h_s[(w * 32 + bl) * 72 + (((j >> 3) ^ (bl & 7)) << 3) + (j & 7)] =
            (short)f2bf(fmaxf(acc1[nt][r] + b1v[nt], 0.0f));
      }
    }

    // ---------------- Stage 2: RAD = H . W2^T + b2 (rad stays in registers) ----------------
    const int hbase = (w * 32 + mh * 16 + ln) * 72;
    const s16x8 a20 = *(const s16x8*)&h_s[hbase + (((0 + hi) ^ (ln & 7)) << 3)];
    const s16x8 a21 = *(const s16x8*)&h_s[hbase + (((4 + hi) ^ (ln & 7)) << 3)];
    f32x4 acc2[2] = {};
    acc2[0] = __builtin_amdgcn_mfma_f32_16x16x32_bf16(a20, w2f[0][0], acc2[0], 0, 0, 0);
    acc2[1] = __builtin_amdgcn_mfma_f32_16x16x32_bf16(a20, w2f[1][0], acc2[1], 0, 0, 0);
    acc2[0] = __builtin_amdgcn_mfma_f32_16x16x32_bf16(a21, w2f[0][1], acc2[0], 0, 0, 0);
    acc2[1] = __builtin_amdgcn_mfma_f32_16x16x32_bf16(a21, w2f[1][1], acc2[1], 0, 0, 0);
    float rad0[4], rad1[4];
    #pragma unroll
    for (int e = 0; e < 4; ++e) { rad0[e] = acc2[0][e] + b2v[0]; rad1[e] = acc2[1][e] + b2v[1]; }
    // lane (ln,hi) holds rad[c=ln | 16+ln][b = 16mh+4hi .. +3] -- exactly stage-3 ownership.

    // ---------------- role-conditional LDS reads (all bank-clean, see layout pads) ----------------
    const int bl4 = mh * 16 + hi * 4;
    float uu[4][3];
    if (w != 0) {
      #pragma unroll
      for (int e = 0; e < 4; ++e) {
        const f32x4 uv = *(const f32x4*)&u_lds[buf][bl4 + e][0];  // 4-addr broadcast
        uu[e][0] = uv[0]; uu[e][1] = uv[1]; uu[e][2] = uv[2];
      }
    }
    float x0r0[4], x0r1[4], x1r0[4][3], x1r1[4][3];
    if (w <= 1) {
      #pragma unroll
      for (int e = 0; e < 4; ++e) {
        x0r0[e] = x0_s[buf][bl4 + e][ln];
        x0r1[e] = x0_s[buf][bl4 + e][16 + ln];
      }
    }
    if (w != 1) {
      #pragma unroll
      for (int e = 0; e < 4; ++e)
        #pragma unroll
        for (int i = 0; i < 3; ++i) {
          x1r0[e][i] = x1_s[buf][bl4 + e][3 * ln + i];
          x1r1[e][i] = x1_s[buf][bl4 + e][48 + 3 * ln + i];
        }
    }

    // ---------------- Stage 3: per-wave equivariant accumulation (pure registers) ----------------
    if (w == 0) {            // r0: out0_a += r0*x0 ; out1_b += r0*x1
      #pragma unroll
      for (int e = 0; e < 4; ++e) {
        const float r = rad0[e];
        av[0] = fmaf(r, x0r0[e],    av[0]);
        av[1] = fmaf(r, x1r0[e][0], av[1]);
        av[2] = fmaf(r, x1r0[e][1], av[2]);
        av[3] = fmaf(r, x1r0[e][2], av[3]);
        const float s = rad1[e];
        av[4] = fmaf(s, x0r1[e],    av[4]);
        av[5] = fmaf(s, x1r1[e][0], av[5]);
        av[6] = fmaf(s, x1r1[e][1], av[6]);
        av[7] = fmaf(s, x1r1[e][2], av[7]);
      }
    } else if (w == 1) {     // ra: out1_a += ra*x0*u
      #pragma unroll
      for (int e = 0; e < 4; ++e) {
        const float rx0 = rad0[e] * x0r0[e];
        av[0] = fmaf(rx0, uu[e][0], av[0]);
        av[1] = fmaf(rx0, uu[e][1], av[1]);
        av[2] = fmaf(rx0, uu[e][2], av[2]);
        const float rx1 = rad1[e] * x0r1[e];
        av[3] = fmaf(rx1, uu[e][0], av[3]);
        av[4] = fmaf(rx1, uu[e][1], av[4]);
        av[5] = fmaf(rx1, uu[e][2], av[5]);
      }
    } else if (w == 2) {     // rb: out0_b += rb*(u . x1)
      #pragma unroll
      for (int e = 0; e < 4; ++e) {
        const float dot0 = fmaf(uu[e][0], x1r0[e][0], fmaf(uu[e][1], x1r0[e][1], uu[e][2] * x1r0[e][2]));
        av[0] = fmaf(rad0[e], dot0, av[0]);
        const float dot1 = fmaf(uu[e][0], x1r1[e][0], fmaf(uu[e][1], x1r1[e][1], uu[e][2] * x1r1[e][2]));
        av[1] = fmaf(rad1[e], dot1, av[1]);
      }
    } else {                 // rc: out1_c += rc*(u x x1)
      #pragma unroll
      for (int e = 0; e < 4; ++e) {
        #pragma unroll
        for (int i = 0; i < 3; ++i) {
          const int j = (i + 1) % 3, k = (i + 2) % 3;
          const float cr0 = fmaf(uu[e][j], x1r0[e][k], -(uu[e][k] * x1r0[e][j]));
          av[i] = fmaf(rad0[e], cr0, av[i]);
          const float cr1 = fmaf(uu[e][j], x1r1[e][k], -(uu[e][k] * x1r1[e][j]));
          av[3 + i] = fmaf(rad1[e], cr1, av[3 + i]);
        }
      }
    }
  }

  // ---------------- reduce over hi (shfl) and mh (LDS), then store ----------------
  #pragma unroll
  for (int q = 0; q < 8; ++q) {
    av[q] += __shfl_xor(av[q], 16);
    av[q] += __shfl_xor(av[q], 32);
  }
  if (mh == 1 && hi == 0) {
    #pragma unroll
    for (int q = 0; q < 8; ++q) scr[w][ln][q] = av[q];
  }
  __syncthreads();
  if (mh == 0 && hi == 0) {
    #pragma unroll
    for (int q = 0; q < 8; ++q) av[q] += scr[w][ln][q];
    float* o1 = out + NATOM * 64 + a * 288;   // out1 [512][96][3]
    if (w == 0) {
      out[a * 64 + ln]      = av[0];
      o1[(32 + ln) * 3 + 0] = av[1]; o1[(32 + ln) * 3 + 1] = av[2]; o1[(32 + ln) * 3 + 2] = av[3];
      out[a * 64 + 16 + ln] = av[4];
      o1[(48 + ln) * 3 + 0] = av[5]; o1[(48 + ln) * 3 + 1] = av[6]; o1[(48 + ln) * 3 + 2] = av[7];
    } else if (w == 1) {
      o1[(     ln) * 3 + 0] = av[0]; o1[(     ln) * 3 + 1] = av[1]; o1[(     ln) * 3 + 2] = av[2];
      o1[(16 + ln) * 3 + 0] = av[3]; o1[(16 + ln) * 3 + 1] = av[4]; o1[(16 + ln) * 3 + 2] = av[5];
    } else if (w == 2) {
      out[a * 64 + 32 + ln] = av[0];
      out[a * 64 + 48 + ln] = av[1];
    } else {
      o1[(64 + ln) * 3 + 0] = av[0]; o1[(64 + ln) * 3 + 1] = av[1]; o1[(64 + ln) * 3 + 2] = av[2];
      o1[(80 + ln) * 3 + 0] = av[3]; o1[(80 + ln) * 3 + 1] = av[4]; o1[(80 + ln) * 3 + 2] = av[5];
    }
  }
}

} // namespace

extern "C" void kernel_launch(void* const* d_in, const int* in_sizes, int n_in,
                              void* d_out, int out_size, void* d_ws, size_t ws_size,
                              hipStream_t stream) {
  (void)in_sizes; (void)n_in; (void)d_ws; (void)ws_size; (void)out_size;
  Ptrs A;
  for (int i = 0; i < 19; ++i) A.p[i] = (const float*)d_in[i];
  tfn_fused<<<dim3(NATOM), dim3(512), 0, stream>>>(A, (float*)d_out);
}

// Round 6
// 146.080 us; speedup vs baseline: 2.0917x; 2.0722x over previous
//
#include <hip/hip_runtime.h>
#include <math.h>

namespace {

constexpr int NATOM = 512;
constexpr float STEP = 10.0f / 63.0f;

typedef float f32x4 __attribute__((ext_vector_type(4)));
typedef short s16x8 __attribute__((ext_vector_type(8)));

struct Ptrs { const float* p[19]; };

// input index map:
// 0 geometry [512,3]; 1 x0 [512,32,1]; 2 x1 [512,32,3]
// then per net q in {f0,fa,fb,fc}: 3+4q w1[64,64]; 4+4q b1[64]; 5+4q w2[32,64]; 6+4q b2[32]

__device__ __forceinline__ unsigned f2bf(float f) {
  union { float f; unsigned u; } v; v.f = f;
  return (v.u + 0x7fffu + ((v.u >> 16) & 1u)) >> 16;  // RNE
}

// NOTE: no min-waves clause. R5's (512,4) pledged 8 waves/SIMD -> 64-VGPR cap ->
// ~360 MB/dispatch scratch spill (WRITE_SIZE evidence). Let RA pick.
__global__ __launch_bounds__(512)
void tfn_fused(Ptrs A, float* __restrict__ out) {
  const int a    = blockIdx.x;
  const int tid  = threadIdx.x;
  const int wv   = tid >> 6;
  const int w    = wv & 3;        // net: 0=f0 1=fa 2=fb 3=fc
  const int mh   = wv >> 2;       // b-half of the 32-neighbor tile
  const int lane = tid & 63;
  const int ln   = lane & 15;
  const int hi   = lane >> 4;     // 0..3

  // ---------------- LDS (~63 KB; 2 blocks/CU) ----------------
  __shared__ __align__(16) short rbf_frag[2][2][2][64][8]; // [dbuf][kt][mt][lane][8] bf16 frag-order
  __shared__ __align__(16) float u_lds[2][32][4];          // [dbuf][b][xyz-]
  __shared__ __align__(16) short h_s[4 * 32 * 72];         // per-net h, XOR-swizzled chunks
  __shared__ __align__(16) float x0_s[2][32][36];          // [dbuf][b][c] pad->stride 36 (4 mod 32)
  __shared__ __align__(16) float x1_s[2][32][100];         // [dbuf][b][c*3+i] pad->stride 100 (4 mod 32)
  __shared__ __align__(16) float scr[4][16][8];            // mh-pair combine

  const float* __restrict__ geom = A.p[0];
  const float* __restrict__ x0g  = A.p[1];
  const float* __restrict__ x1g  = A.p[2];

  // ---------------- persistent register B-fragments (weights, bf16) ----------------
  s16x8 w1f[4][2];
  {
    const float* w1p = A.p[3 + 4 * w];
    #pragma unroll
    for (int nt = 0; nt < 4; ++nt)
      #pragma unroll
      for (int kt = 0; kt < 2; ++kt) {
        const float* src = w1p + (nt * 16 + ln) * 64 + kt * 32 + hi * 8;
        s16x8 f;
        #pragma unroll
        for (int i = 0; i < 8; ++i) f[i] = (short)f2bf(src[i]);
        w1f[nt][kt] = f;
      }
  }
  float b1v[4];
  {
    const float* b1p = A.p[4 + 4 * w];
    #pragma unroll
    for (int nt = 0; nt < 4; ++nt) b1v[nt] = b1p[nt * 16 + ln];
  }
  s16x8 w2f[2][2];
  {
    const float* w2p = A.p[5 + 4 * w];
    #pragma unroll
    for (int nt = 0; nt < 2; ++nt)
      #pragma unroll
      for (int kt = 0; kt < 2; ++kt) {
        const float* src = w2p + (nt * 16 + ln) * 64 + kt * 32 + hi * 8;
        s16x8 f;
        #pragma unroll
        for (int i = 0; i < 8; ++i) f[i] = (short)f2bf(src[i]);
        w2f[nt][kt] = f;
      }
  }
  float b2v[2];
  {
    const float* b2p = A.p[6 + 4 * w];
    b2v[0] = b2p[ln]; b2v[1] = b2p[16 + ln];
  }

  const float gax = geom[3*a+0], gay = geom[3*a+1], gaz = geom[3*a+2];

  const int sb = tid >> 4;        // staging row (neighbor in tile)
  const int sc = tid & 15;        // staging col group

  float av[8] = {0.f,0.f,0.f,0.f,0.f,0.f,0.f,0.f};

  for (int t = 0; t < 16; ++t) {
    const int b0  = t * 32;
    const int buf = t & 1;

    // ---------------- Phase A: staging (rbf frag-order, u, x0, x1) ----------------
    {
      // x0 tile [32][32] -> x0_s (coalesced 64B-segment reads, ~2-way LDS writes)
      #pragma unroll
      for (int s = 0; s < 2; ++s)
        x0_s[buf][sb][sc + 16 * s] = x0g[(b0 + sb) * 32 + sc + 16 * s];
      // x1 tile [32][96] -> x1_s
      #pragma unroll
      for (int s = 0; s < 6; ++s)
        x1_s[buf][sb][sc + 16 * s] = x1g[(b0 + sb) * 96 + sc + 16 * s];

      const int bb = tid & 31;          // neighbor in tile
      const int kq = tid >> 5;          // rbf quad 0..15 (4 centers each)
      const int bg = b0 + bb;
      const float dx = gax - geom[3*bg+0];
      const float dy = gay - geom[3*bg+1];
      const float dz = gaz - geom[3*bg+2];
      const float r2 = dx*dx + dy*dy + dz*dz;
      const float dij = sqrtf(fmaxf(r2, 1e-8f));
      const float d0 = dij - STEP * (float)(4 * kq);
      const float d1 = d0 - STEP, d2 = d0 - 2.f*STEP, d3 = d0 - 3.f*STEP;
      const unsigned lo  = f2bf(__expf(-10.f*d0*d0)) | (f2bf(__expf(-10.f*d1*d1)) << 16);
      const unsigned hi2 = f2bf(__expf(-10.f*d2*d2)) | (f2bf(__expf(-10.f*d3*d3)) << 16);
      uint2 pk; pk.x = lo; pk.y = hi2;
      // frag address: kt=kq>>3, mt=bb>>4, fraglane=((kq>>1)&3)*16+(bb&15), half=kq&1
      *(uint2*)&rbf_frag[buf][kq >> 3][bb >> 4][((kq >> 1) & 3) * 16 + (bb & 15)][(kq & 1) * 4] = pk;
      if (kq == 0) {
        const float inv = 1.0f / sqrtf(r2 + 1e-8f);   // 0*inv=0 on diagonal -> self-mask free
        f32x4 uv; uv[0] = dx*inv; uv[1] = dy*inv; uv[2] = dz*inv; uv[3] = 0.f;
        *(f32x4*)&u_lds[buf][bb][0] = uv;
      }
    }
    __syncthreads();   // the only barrier per tile (2-deep dbuf makes it race-free)

    // ---------------- Stage 1: H = relu(RBF . W1^T + b1) ----------------
    const s16x8 af0 = *(const s16x8*)&rbf_frag[buf][0][mh][lane][0];  // lane-linear, conflict-free
    const s16x8 af1 = *(const s16x8*)&rbf_frag[buf][1][mh][lane][0];
    f32x4 acc1[4] = {};
    #pragma unroll
    for (int nt = 0; nt < 4; ++nt)
      acc1[nt] = __builtin_amdgcn_mfma_f32_16x16x32_bf16(af0, w1f[nt][0], acc1[nt], 0, 0, 0);
    #pragma unroll
    for (int nt = 0; nt < 4; ++nt)
      acc1[nt] = __builtin_amdgcn_mfma_f32_16x16x32_bf16(af1, w1f[nt][1], acc1[nt], 0, 0, 0);
    // bias+relu+cvt, XOR-swizzled scatter (own-wave rows only -> no barrier)
    #pragma unroll
    for (int nt = 0; nt < 4; ++nt) {
      const int j = nt * 16 + ln;
      #pragma unroll
      for (int r = 0; r < 4; ++r) {
        const int bl = mh * 16 + hi * 4 + r;
        h_s[(w * 32 + bl) * 72 + (((j >> 3) ^ (bl & 7)) << 3) + (j & 7)] =
            (short)f2bf(fmaxf(acc1[nt][r] + b1v[nt], 0.0f));
      }
    }

    // ---------------- Stage 2: RAD = H . W2^T + b2 (rad stays in registers) ----------------
    const int hbase = (w * 32 + mh * 16 + ln) * 72;
    const s16x8 a20 = *(const s16x8*)&h_s[hbase + (((0 + hi) ^ (ln & 7)) << 3)];
    const s16x8 a21 = *(const s16x8*)&h_s[hbase + (((4 + hi) ^ (ln & 7)) << 3)];
    f32x4 acc2[2] = {};
    acc2[0] = __builtin_amdgcn_mfma_f32_16x16x32_bf16(a20, w2f[0][0], acc2[0], 0, 0, 0);
    acc2[1] = __builtin_amdgcn_mfma_f32_16x16x32_bf16(a20, w2f[1][0], acc2[1], 0, 0, 0);
    acc2[0] = __builtin_amdgcn_mfma_f32_16x16x32_bf16(a21, w2f[0][1], acc2[0], 0, 0, 0);
    acc2[1] = __builtin_amdgcn_mfma_f32_16x16x32_bf16(a21, w2f[1][1], acc2[1], 0, 0, 0);
    float rad0[4], rad1[4];
    #pragma unroll
    for (int e = 0; e < 4; ++e) { rad0[e] = acc2[0][e] + b2v[0]; rad1[e] = acc2[1][e] + b2v[1]; }
    // lane (ln,hi) holds rad[c=ln | 16+ln][b = 16mh+4hi .. +3] -- exactly stage-3 ownership.

    // ---------------- Stage 3: per-wave accumulation, per-e fused load+FMA ----------------
    // (live set ~14 regs per e-iteration; sched_barrier stops re-hoisting -> no spill)
    const int bl4 = mh * 16 + hi * 4;
    if (w == 0) {            // f0: out0_a += r0*x0 ; out1_b += r0*x1
      #pragma unroll
      for (int e = 0; e < 4; ++e) {
        const int b = bl4 + e;
        const float r = rad0[e], s = rad1[e];
        av[0] = fmaf(r, x0_s[buf][b][ln],          av[0]);
        av[1] = fmaf(r, x1_s[buf][b][3*ln+0],      av[1]);
        av[2] = fmaf(r, x1_s[buf][b][3*ln+1],      av[2]);
        av[3] = fmaf(r, x1_s[buf][b][3*ln+2],      av[3]);
        av[4] = fmaf(s, x0_s[buf][b][16+ln],       av[4]);
        av[5] = fmaf(s, x1_s[buf][b][48+3*ln+0],   av[5]);
        av[6] = fmaf(s, x1_s[buf][b][48+3*ln+1],   av[6]);
        av[7] = fmaf(s, x1_s[buf][b][48+3*ln+2],   av[7]);
        __builtin_amdgcn_sched_barrier(0);
      }
    } else if (w == 1) {     // fa: out1_a += ra*x0*u
      #pragma unroll
      for (int e = 0; e < 4; ++e) {
        const int b = bl4 + e;
        const f32x4 uv = *(const f32x4*)&u_lds[buf][b][0];
        const float rx0 = rad0[e] * x0_s[buf][b][ln];
        av[0] = fmaf(rx0, uv[0], av[0]);
        av[1] = fmaf(rx0, uv[1], av[1]);
        av[2] = fmaf(rx0, uv[2], av[2]);
        const float rx1 = rad1[e] * x0_s[buf][b][16+ln];
        av[3] = fmaf(rx1, uv[0], av[3]);
        av[4] = fmaf(rx1, uv[1], av[4]);
        av[5] = fmaf(rx1, uv[2], av[5]);
        __builtin_amdgcn_sched_barrier(0);
      }
    } else if (w == 2) {     // fb: out0_b += rb*(u . x1)
      #pragma unroll
      for (int e = 0; e < 4; ++e) {
        const int b = bl4 + e;
        const f32x4 uv = *(const f32x4*)&u_lds[buf][b][0];
        const float dot0 = fmaf(uv[0], x1_s[buf][b][3*ln+0],
                           fmaf(uv[1], x1_s[buf][b][3*ln+1],
                                uv[2] * x1_s[buf][b][3*ln+2]));
        av[0] = fmaf(rad0[e], dot0, av[0]);
        const float dot1 = fmaf(uv[0], x1_s[buf][b][48+3*ln+0],
                           fmaf(uv[1], x1_s[buf][b][48+3*ln+1],
                                uv[2] * x1_s[buf][b][48+3*ln+2]));
        av[1] = fmaf(rad1[e], dot1, av[1]);
        __builtin_amdgcn_sched_barrier(0);
      }
    } else {                 // fc: out1_c += rc*(u x x1)
      #pragma unroll
      for (int e = 0; e < 4; ++e) {
        const int b = bl4 + e;
        const f32x4 uv = *(const f32x4*)&u_lds[buf][b][0];
        {
          const float xa = x1_s[buf][b][3*ln+0];
          const float xb = x1_s[buf][b][3*ln+1];
          const float xc = x1_s[buf][b][3*ln+2];
          const float r  = rad0[e];
          av[0] = fmaf(r, fmaf(uv[1], xc, -(uv[2] * xb)), av[0]);
          av[1] = fmaf(r, fmaf(uv[2], xa, -(uv[0] * xc)), av[1]);
          av[2] = fmaf(r, fmaf(uv[0], xb, -(uv[1] * xa)), av[2]);
        }
        {
          const float xa = x1_s[buf][b][48+3*ln+0];
          const float xb = x1_s[buf][b][48+3*ln+1];
          const float xc = x1_s[buf][b][48+3*ln+2];
          const float r  = rad1[e];
          av[3] = fmaf(r, fmaf(uv[1], xc, -(uv[2] * xb)), av[3]);
          av[4] = fmaf(r, fmaf(uv[2], xa, -(uv[0] * xc)), av[4]);
          av[5] = fmaf(r, fmaf(uv[0], xb, -(uv[1] * xa)), av[5]);
        }
        __builtin_amdgcn_sched_barrier(0);
      }
    }
  }

  // ---------------- reduce over hi (shfl) and mh (LDS), then store ----------------
  #pragma unroll
  for (int q = 0; q < 8; ++q) {
    av[q] += __shfl_xor(av[q], 16);
    av[q] += __shfl_xor(av[q], 32);
  }
  if (mh == 1 && hi == 0) {
    #pragma unroll
    for (int q = 0; q < 8; ++q) scr[w][ln][q] = av[q];
  }
  __syncthreads();
  if (mh == 0 && hi == 0) {
    #pragma unroll
    for (int q = 0; q < 8; ++q) av[q] += scr[w][ln][q];
    float* o1 = out + NATOM * 64 + a * 288;   // out1 [512][96][3]
    if (w == 0) {
      out[a * 64 + ln]      = av[0];
      o1[(32 + ln) * 3 + 0] = av[1]; o1[(32 + ln) * 3 + 1] = av[2]; o1[(32 + ln) * 3 + 2] = av[3];
      out[a * 64 + 16 + ln] = av[4];
      o1[(48 + ln) * 3 + 0] = av[5]; o1[(48 + ln) * 3 + 1] = av[6]; o1[(48 + ln) * 3 + 2] = av[7];
    } else if (w == 1) {
      o1[(     ln) * 3 + 0] = av[0]; o1[(     ln) * 3 + 1] = av[1]; o1[(     ln) * 3 + 2] = av[2];
      o1[(16 + ln) * 3 + 0] = av[3]; o1[(16 + ln) * 3 + 1] = av[4]; o1[(16 + ln) * 3 + 2] = av[5];
    } else if (w == 2) {
      out[a * 64 + 32 + ln] = av[0];
      out[a * 64 + 48 + ln] = av[1];
    } else {
      o1[(64 + ln) * 3 + 0] = av[0]; o1[(64 + ln) * 3 + 1] = av[1]; o1[(64 + ln) * 3 + 2] = av[2];
      o1[(80 + ln) * 3 + 0] = av[3]; o1[(80 + ln) * 3 + 1] = av[4]; o1[(80 + ln) * 3 + 2] = av[5];
    }
  }
}

} // namespace

extern "C" void kernel_launch(void* const* d_in, const int* in_sizes, int n_in,
                              void* d_out, int out_size, void* d_ws, size_t ws_size,
                              hipStream_t stream) {
  (void)in_sizes; (void)n_in; (void)d_ws; (void)ws_size; (void)out_size;
  Ptrs A;
  for (int i = 0; i < 19; ++i) A.p[i] = (const float*)d_in[i];
  tfn_fused<<<dim3(NATOM), dim3(512), 0, stream>>>(A, (float*)d_out);
}